// Round 18
// baseline (384.329 us; speedup 1.0000x reference)
//
#include <hip/hip_runtime.h>
#include <math.h>

#define N_NODES 50000
#define N_EDGES 600000
#define F_INPUT 128
#define HCDIM 256
#define NGRAPH 64
#define NCLS 3
#define MPAD 50048   // 782 * 64, GEMM M padded
#define SCAN_NB ((N_NODES + 255) / 256)   // 196
#define LOG2E 1.4426950408889634f
#define NPART 32     // pooling partitions per graph
#define TOTAL_E (N_EDGES + N_NODES)
#define PLANE64 ((size_t)N_NODES * 64)    // bytes (fp8) / elements per head plane
#define EDGE_CHUNKS ((N_NODES + 63) / 64) // 782
#define DBINS 64     // degree-sort bins (deg clamped to 63 for binning only)
#define BSEG (SCAN_NB / 4)   // 49 blocks per scan segment (196 = 4*49)
#define GEMM_NB ((MPAD / 64) * 4)   // 3128 blocks = 8 XCDs * 391
#define GEMM_QPX (GEMM_NB / 8)      // 391 blocks per XCD (exact)
#define BUCKET 64                    // colx slots per node (max deg ~35 << 64)
#define COLX_SZ (N_NODES * BUCKET + 128)  // +128 zero pad for prefetch overrun
#define NPX ((N_NODES + 7) / 8)      // 6250 nodes per XCD partition
#define SA_SZ (64 * 64)              // one A LDS buffer (elems)
#define SB_SZ (128 * 64)             // one B LDS buffer (elems)

// ---- fused hist+boundary+prep: XCD-partitioned single-pass bucket CSR scatter ----
#define HIST_CH   ((TOTAL_E + 255) / 256)               // 2540 chunks
#define HIST_NB   (HIST_CH * 8)                         // 20320
#define BND_NB    ((N_NODES + 255) / 256)               // 196
#define SPLITX_NB (MPAD * F_INPUT / 4 / 256)            // 6256
#define ZERO_NB   (((MPAD - N_NODES) * HCDIM / 4 + 255) / 256)  // 12
#define WPREP_NB  (512 * (F_INPUT + HCDIM + HCDIM) / 256)       // 1280
#define HP_NB     (HIST_NB + BND_NB + SPLITX_NB + ZERO_NB + WPREP_NB)
// ---- fused meta-scatter + gemm0 ----
#define FG_NB     (SCAN_NB + GEMM_NB)                   // 3324

typedef float f32x4 __attribute__((ext_vector_type(4)));
typedef float f32x2 __attribute__((ext_vector_type(2)));
typedef _Float16 f16x8 __attribute__((ext_vector_type(8)));
typedef _Float16 f16x4 __attribute__((ext_vector_type(4)));
typedef _Float16 h2 __attribute__((ext_vector_type(2)));

__device__ __forceinline__ void gl_lds16(const void* g, void* l) {
    __builtin_amdgcn_global_load_lds(
        (const __attribute__((address_space(1))) unsigned int*)g,
        (__attribute__((address_space(3))) unsigned int*)l, 16, 0, 0);
}

__device__ __forceinline__ h2 bch2(unsigned int u) { return __builtin_bit_cast(h2, u); }
__device__ __forceinline__ h2 pk16(float a, float b) {
    return __builtin_bit_cast(h2, __builtin_amdgcn_cvt_pkrtz(a, b));
}

// 4-lane (quad) butterfly sum via DPP quad_perm — pure VALU, no LDS pipe / lgkm wait.
__device__ __forceinline__ float quad_reduce_add(float p) {
    int s1 = __builtin_amdgcn_update_dpp(0, __builtin_bit_cast(int, p), 0xB1, 0xF, 0xF, true);
    p += __builtin_bit_cast(float, s1);
    int s2 = __builtin_amdgcn_update_dpp(0, __builtin_bit_cast(int, p), 0x4E, 0xF, 0xF, true);
    p += __builtin_bit_cast(float, s2);
    return p;
}

// 64x128-tile GEMM body, BK=64, T3 minimal 2-phase DOUBLE-BUFFERED schedule:
//   stage(buf0); barrier; loop t: { stage(buf^1, t+1); compute(buf); barrier; swap }
// Next-tile loads are in flight DURING the current tile's MFMA, so the barrier's
// vmcnt(0) drain only covers the latency remaining after ~320cy of compute
// (previously the full ~600-900cy drain was exposed 4x per GEMM: MfmaUtil 11%).
// Geometry unchanged — three chunkier variants (BN=256, 128x128, BK=128) all
// measured worse; this changes SCHEDULE only. LDS 48KB -> 3 blocks/CU ceiling,
// above measured ~2.3 residency. Staging burst stays 6 gl_lds16.
__device__ __forceinline__ void gemm_body_64(
    const _Float16* __restrict__ A, const _Float16* __restrict__ B, int K,
    const float* __restrict__ bl, const float* __restrict__ br,
    unsigned char* __restrict__ xl8, _Float16* __restrict__ xrh,
    _Float16* sA, _Float16* sB, int bx, int by)
{
    int tid = threadIdx.x;
    int lane = tid & 63, wave = tid >> 6;
    int wm = wave >> 1, wn = wave & 1;
    int row0 = bx * 64;
    int n0 = by * 128;
    int quad = lane >> 4, l16 = lane & 15;

    f32x4 acc[2][4];
    #pragma unroll
    for (int i = 0; i < 2; ++i)
        #pragma unroll
        for (int j = 0; j < 4; ++j)
            acc[i][j] = (f32x4){0.f, 0.f, 0.f, 0.f};

    auto stage = [&](int buf, int k0) {
        _Float16* dA = sA + buf * SA_SZ;
        _Float16* dB = sB + buf * SB_SZ;
        #pragma unroll
        for (int pass = 0; pass < 2; ++pass) {
            int c = tid + pass * 256;           // A chunk 0..511
            int r = c >> 3;
            int pl = c & 7;
            int pg = pl ^ (r & 7);
            gl_lds16(A + (size_t)(row0 + r) * K + k0 + pg * 8, dA + c * 8);
        }
        #pragma unroll
        for (int pass = 0; pass < 4; ++pass) {
            int c = tid + pass * 256;           // B chunk 0..1023
            int r = c >> 3;
            int pl = c & 7;
            int pg = pl ^ (r & 7);
            gl_lds16(B + (size_t)(n0 + r) * K + k0 + pg * 8, dB + c * 8);
        }
    };

    stage(0, 0);
    __syncthreads();                            // drain tile-0 loads
    int nt = K >> 6;
    int cur = 0;
    for (int t = 0; t < nt; ++t) {
        if (t + 1 < nt) stage(cur ^ 1, (t + 1) << 6);   // issue next-tile loads FIRST
        const _Float16* cA = sA + cur * SA_SZ;
        const _Float16* cB = sB + cur * SB_SZ;
        #pragma unroll
        for (int kk = 0; kk < 2; ++kk) {
            f16x8 fa[2], fb[4];
            #pragma unroll
            for (int i = 0; i < 2; ++i) {
                int rr = wm * 32 + i * 16 + l16;
                int ca = (kk * 4 + quad) ^ (rr & 7);
                fa[i] = *(const f16x8*)&cA[rr * 64 + ca * 8];
            }
            #pragma unroll
            for (int j = 0; j < 4; ++j) {
                int nn = wn * 64 + j * 16 + l16;
                int cb = (kk * 4 + quad) ^ (nn & 7);
                fb[j] = *(const f16x8*)&cB[nn * 64 + cb * 8];
            }
            #pragma unroll
            for (int i = 0; i < 2; ++i)
                #pragma unroll
                for (int j = 0; j < 4; ++j)
                    acc[i][j] = __builtin_amdgcn_mfma_f32_16x16x32_f16(fa[i], fb[j], acc[i][j], 0, 0, 0);
        }
        __syncthreads();   // drains next-tile loads (vmcnt0) + protects buf reuse
        cur ^= 1;
    }

    if (by < 2) {
        int cb0 = by * 128;
        #pragma unroll
        for (int j = 0; j < 4; ++j) {
            int col = cb0 + wn * 64 + j * 16 + l16;
            float bj = bl[col];
            int hh = col >> 6, c64 = col & 63;
            unsigned char* xlp = xl8 + (size_t)hh * PLANE64;
            #pragma unroll
            for (int i = 0; i < 2; ++i) {
                int rbase = row0 + wm * 32 + i * 16 + quad * 4;
                #pragma unroll
                for (int r = 0; r < 4; ++r) {
                    int row = rbase + r;
                    if (row < N_NODES) {
                        float v = acc[i][j][r] + bj;
                        int pk = __builtin_amdgcn_cvt_pk_fp8_f32(v, v, 0, false);
                        xlp[(size_t)row * 64 + c64] = (unsigned char)pk;
                    }
                }
            }
        }
    } else {
        int cb0 = (by - 2) * 128;
        #pragma unroll
        for (int j = 0; j < 4; ++j) {
            int col = cb0 + wn * 64 + j * 16 + l16;
            float bj = br[col];
            int hh = col >> 6, c64 = col & 63;
            _Float16* xrp = xrh + (size_t)hh * PLANE64;
            #pragma unroll
            for (int i = 0; i < 2; ++i) {
                int rbase = row0 + wm * 32 + i * 16 + quad * 4;
                #pragma unroll
                for (int r = 0; r < 4; ++r) {
                    int row = rbase + r;
                    if (row < N_NODES)
                        xrp[(size_t)row * 64 + c64] = (_Float16)(acc[i][j][r] + bj);
                }
            }
        }
    }
}

// ============================ Fused bucket-CSR scatter + boundary + prep ============================
__global__ void hist_prep_kernel(
    const int* __restrict__ ei, int* __restrict__ cnt, int* __restrict__ colx,
    const int* __restrict__ batch, int* __restrict__ startg, int* __restrict__ endg,
    const float* __restrict__ x, _Float16* __restrict__ A,
    _Float16* __restrict__ Bt0, _Float16* __restrict__ Bt1, _Float16* __restrict__ Bt2,
    const float* __restrict__ Wl0, const float* __restrict__ Wr0,
    const float* __restrict__ Wl1, const float* __restrict__ Wr1,
    const float* __restrict__ Wl2, const float* __restrict__ Wr2)
{
    int b = blockIdx.x;
    if (b < HIST_NB) {
        // XCD-local scatter: this block handles only dests in its XCD's node range.
        int xcd = b & 7;                       // bid%8 = XCD (round-robin dispatch)
        int i = (b >> 3) * 256 + threadIdx.x;  // edge chunk
        if (i >= TOTAL_E) return;
        int s, d;
        if (i < N_EDGES) { s = ei[i]; d = ei[N_EDGES + i]; }
        else             { s = i - N_EDGES; d = s; }
        if ((unsigned)(d - xcd * NPX) < (unsigned)NPX) {
            int slot = atomicAdd(&cnt[d], 1);
            colx[d * BUCKET + slot] = s * 64;
        }
        return;
    }
    b -= HIST_NB;
    if (b < BND_NB) {
        int i = b * 256 + threadIdx.x;
        if (i >= N_NODES) return;
        int g = batch[i];
        if (i == 0 || batch[i - 1] != g) startg[g] = i;
        if (i == N_NODES - 1 || batch[i + 1] != g) endg[g] = i + 1;
        return;
    }
    b -= BND_NB;
    if (b < SPLITX_NB) {
        int base = (b * 256 + threadIdx.x) * 4;
        int row = base >> 7;
        float4 v = make_float4(0.f, 0.f, 0.f, 0.f);
        if (row < N_NODES) v = *(const float4*)&x[base];
        f16x4 o;
        o.x = (_Float16)v.x; o.y = (_Float16)v.y; o.z = (_Float16)v.z; o.w = (_Float16)v.w;
        *(f16x4*)&A[base] = o;
    } else if (b < SPLITX_NB + ZERO_NB) {
        int i = ((b - SPLITX_NB) * 256 + threadIdx.x) * 4;
        if (i < (MPAD - N_NODES) * HCDIM) {
            f16x4 z = {(_Float16)0.f, (_Float16)0.f, (_Float16)0.f, (_Float16)0.f};
            *(f16x4*)&A[(size_t)N_NODES * HCDIM + i] = z;
        }
    } else {
        int t = (b - SPLITX_NB - ZERO_NB) * 256 + threadIdx.x;
        const float* Wl; const float* Wr; _Float16* Bt; int K;
        if (t < 512 * F_INPUT)            { Wl = Wl0; Wr = Wr0; Bt = Bt0; K = F_INPUT; }
        else if (t < 512 * (F_INPUT + HCDIM)) { t -= 512 * F_INPUT; Wl = Wl1; Wr = Wr1; Bt = Bt1; K = HCDIM; }
        else                              { t -= 512 * (F_INPUT + HCDIM); Wl = Wl2; Wr = Wr2; Bt = Bt2; K = HCDIM; }
        int n = t & 511, k = t >> 9;
        float w = (n < 256) ? Wl[k * 256 + n] : Wr[k * 256 + (n - 256)];
        Bt[n * K + k] = (_Float16)w;
    }
}

// Per-block degree histogram for the counting sort.
__global__ void degh_kernel(const int* __restrict__ cnt, int* __restrict__ dhist,
                            int* __restrict__ bcnt) {
    __shared__ int lh[DBINS];
    int b = blockIdx.x, t = threadIdx.x;
    if (t < DBINS) lh[t] = 0;
    __syncthreads();
    int i = b * 256 + t;
    if (i < N_NODES) {
        int dg = cnt[i];
        atomicAdd(&lh[dg < (DBINS - 1) ? dg : (DBINS - 1)], 1);
    }
    __syncthreads();
    if (t < DBINS) {
        bcnt[b * DBINS + t] = lh[t];
        if (lh[t] != 0) atomicAdd(&dhist[t], lh[t]);
    }
}

// Parallel counting-sort level 1 (one block)
__global__ __launch_bounds__(256) void binscan_kernel(const int* __restrict__ dhist,
                                                      int* __restrict__ bcnt) {
    __shared__ int sb[SCAN_NB * DBINS];   // 49.0 KB
    __shared__ int part[4][DBINS];
    __shared__ int binstart[DBINS];
    int t = threadIdx.x;
    for (int i = t; i < SCAN_NB * DBINS; i += 256) sb[i] = bcnt[i];
    if (t < 64) {
        int x = dhist[t];
        #pragma unroll
        for (int off = 1; off < 64; off <<= 1) {
            int y = __shfl_up(x, off, 64);
            if (t >= off) x += y;
        }
        int total = __shfl(x, 63, 64);
        binstart[t] = total - x;   // nodes with bin > t (descending order start)
    }
    __syncthreads();
    int l = t & 63, seg = t >> 6;
    int ps = 0;
    for (int b = seg * BSEG; b < (seg + 1) * BSEG; ++b) ps += sb[b * DBINS + l];
    part[seg][l] = ps;
    __syncthreads();
    int off = binstart[l];
    for (int s = 0; s < seg; ++s) off += part[s][l];
    for (int b = seg * BSEG; b < (seg + 1) * BSEG; ++b) {
        int tv = sb[b * DBINS + l];
        sb[b * DBINS + l] = off;
        off += tv;
    }
    __syncthreads();
    for (int i = t; i < SCAN_NB * DBINS; i += 256) bcnt[i] = sb[i];
}

// ============================ Fused meta-scatter + layer-0 GEMM ============================
__global__ __launch_bounds__(256) void fill_gemm_kernel(
    const int* __restrict__ cnt, const int* __restrict__ bcnt, int* __restrict__ meta,
    const _Float16* __restrict__ A, const _Float16* __restrict__ B,
    const float* __restrict__ bl, const float* __restrict__ br,
    unsigned char* __restrict__ xl8, _Float16* __restrict__ xrh)
{
    __shared__ _Float16 sA[2 * SA_SZ], sB[2 * SB_SZ];
    int bid = blockIdx.x;
    if (bid < SCAN_NB) {
        int* lcnt = (int*)sA;
        int t = threadIdx.x;
        if (t < DBINS) lcnt[t] = 0;
        __syncthreads();
        int i = bid * 256 + t;
        if (i < N_NODES) {
            int dg = cnt[i];
            int bin = dg < (DBINS - 1) ? dg : (DBINS - 1);
            int myr = atomicAdd(&lcnt[bin], 1);   // LDS atomic, intra-block only
            int pos = bcnt[bid * DBINS + bin] + myr;
            meta[pos] = (dg << 16) | i;
        }
        return;
    }
    int gbid = bid - SCAN_NB;
    int lin = (gbid & 7) * GEMM_QPX + (gbid >> 3);   // bijective: 3128 = 8*391
    gemm_body_64(A, B, F_INPUT, bl, br, xl8, xrh, sA, sB, lin >> 2, lin & 3);
}

// ============================ 64x128 MFMA GEMM (layers 1-2) ============================
__global__ __launch_bounds__(256) void gemm_mfma(
    const _Float16* __restrict__ A, const _Float16* __restrict__ B,
    int K,
    const float* __restrict__ bl, const float* __restrict__ br,
    unsigned char* __restrict__ xl8, _Float16* __restrict__ xrh)
{
    __shared__ _Float16 sA[2 * SA_SZ], sB[2 * SB_SZ];
    int bid = blockIdx.x;
    int lin = (bid & 7) * GEMM_QPX + (bid >> 3);   // bijective: 3128 = 8*391
    gemm_body_64(A, B, K, bl, br, xl8, xrh, sA, sB, lin >> 2, lin & 3);
}

// ============================ Edge phase: head planes + degree-sorted slots ============================
// Bucket CSR: node's edges at colx[node*64 .. node*64+cnt); slots beyond cnt are 0
// and overrun prefetch reads the next node's bucket / zero pad — always a valid
// plane offset, masked by (i < cnt). 4-deep gather pipeline, 2-edge unrolled, DPP.
__global__ __launch_bounds__(256) void gat_edge(
    const unsigned char* __restrict__ xl8, const _Float16* __restrict__ xrh,
    const float* __restrict__ att, const float* __restrict__ bias,
    const int* __restrict__ meta, const int* __restrict__ colx,
    _Float16* __restrict__ outh, _Float16* __restrict__ onext, int mode)
{
    int head = blockIdx.x & 3;
    int chunk = blockIdx.x >> 2;
    int wave = threadIdx.x >> 6;
    int lane = threadIdx.x & 63;
    int g  = lane >> 2;          // slot within wave (0..15)
    int ll = lane & 3;           // 16-ch slot within head
    int slot = chunk * 64 + wave * 16 + g;
    bool valid = slot < N_NODES;
    int saddr = valid ? slot : 0;
    int mi = meta[saddr];
    int node = mi & 0xFFFF;
    int cnt = valid ? (mi >> 16) : 0;
    int ch0 = head * 64 + ll * 16;

    int niter = cnt;
    niter = max(niter, __shfl_xor(niter, 4, 64));
    niter = max(niter, __shfl_xor(niter, 8, 64));
    niter = max(niter, __shfl_xor(niter, 16, 64));
    niter = max(niter, __shfl_xor(niter, 32, 64));

    const char* xrrow = (const char*)(xrh + (size_t)head * PLANE64)
                        + ((size_t)node * 64 + ll * 16) * 2;
    uint4 xu0 = *(const uint4*)xrrow;
    uint4 xu1 = *(const uint4*)(xrrow + 16);
    h2 xr[8] = { bch2(xu0.x), bch2(xu0.y), bch2(xu0.z), bch2(xu0.w),
                 bch2(xu1.x), bch2(xu1.y), bch2(xu1.z), bch2(xu1.w) };
    h2 at[8];
    #pragma unroll
    for (int i = 0; i < 8; ++i) {
        float2 av = *(const float2*)&att[ch0 + i * 2];
        at[i] = (h2){(_Float16)(av.x * LOG2E), (_Float16)(av.y * LOG2E)};
    }

    float denom = 0.f;
    f32x2 accp[8];
    #pragma unroll
    for (int i = 0; i < 8; ++i) accp[i] = (f32x2){0.f, 0.f};

    const unsigned char* xb = xl8 + (size_t)head * PLANE64 + ll * 16;
    const int* cxp = colx + (node << 6);   // this node's bucket
    const h2 slope = {(_Float16)0.2f, (_Float16)0.2f};

    auto process = [&](uint4 dd, int i) {
        unsigned int dw[4] = {dd.x, dd.y, dd.z, dd.w};
        f32x2 lo[4], hi[4];
        h2 hx[8];
        #pragma unroll
        for (int j = 0; j < 4; ++j) {
            lo[j] = __builtin_amdgcn_cvt_pk_f32_fp8(dw[j], false);
            hi[j] = __builtin_amdgcn_cvt_pk_f32_fp8(dw[j], true);
            hx[2 * j]     = pk16(lo[j].x, lo[j].y);
            hx[2 * j + 1] = pk16(hi[j].x, hi[j].y);
        }
        float pa = 0.f, pb = 0.f;
        #pragma unroll
        for (int j = 0; j < 4; ++j) {
            h2 va = hx[j] + xr[j];
            h2 vb = hx[j + 4] + xr[j + 4];
            va = __builtin_elementwise_max(va, va * slope);   // lrelu(0.2) = max(v, 0.2v)
            vb = __builtin_elementwise_max(vb, vb * slope);
            pa = __builtin_amdgcn_fdot2(va, at[j], pa, false);
            pb = __builtin_amdgcn_fdot2(vb, at[j + 4], pb, false);
        }
        float p = quad_reduce_add(pa + pb);
        float w = (i < cnt) ? exp2f(p) : 0.f;
        denom += w;
        f32x2 wp = {w, w};
        #pragma unroll
        for (int j = 0; j < 4; ++j) {
            accp[2 * j]     += wp * lo[j];   // -> v_pk_fma_f32
            accp[2 * j + 1] += wp * hi[j];
        }
    };

    // pipeline prologue: 4 gathers in flight (edges 0..3), colx staged for 4,5.
    uint4 d0 = *(const uint4*)(xb + (unsigned)cxp[0]);
    uint4 d1 = *(const uint4*)(xb + (unsigned)cxp[1]);
    uint4 d2 = *(const uint4*)(xb + (unsigned)cxp[2]);
    uint4 d3 = *(const uint4*)(xb + (unsigned)cxp[3]);
    int cx_a = cxp[4];
    int cx_b = cxp[5];

    int i = 0;
    for (; i + 2 <= niter; i += 2) {
        uint4 n0 = *(const uint4*)(xb + (unsigned)cx_a);   // gathers edges i+4, i+5
        uint4 n1 = *(const uint4*)(xb + (unsigned)cx_b);
        cx_a = cxp[i + 6];       // overrun lands in next bucket / zero pad — safe
        cx_b = cxp[i + 7];
        process(d0, i);          // two independent chains -> ILP
        process(d1, i + 1);
        d0 = d2; d1 = d3;        // rotate the 4-deep gather queue
        d2 = n0; d3 = n1;
    }
    if (i < niter) process(d0, i);   // odd tail (gather already in flight)

    if (valid) {
        float inv = 1.f / denom;
        char* orow = (char*)(mode == 0 ? outh : onext)
                     + (size_t)node * (HCDIM * 2) + ch0 * 2;
        h2 o[8];
        #pragma unroll
        for (int i2 = 0; i2 < 8; ++i2) {
            float2 bv = *(const float2*)&bias[ch0 + i2 * 2];
            float v0 = accp[i2].x * inv + bv.x;
            float v1 = accp[i2].y * inv + bv.y;
            if (mode != 0) { v0 = fmaxf(v0, 0.f); v1 = fmaxf(v1, 0.f); }
            o[i2] = pk16(v0, v1);
        }
        uint4 s0 = { __builtin_bit_cast(unsigned int, o[0]), __builtin_bit_cast(unsigned int, o[1]),
                     __builtin_bit_cast(unsigned int, o[2]), __builtin_bit_cast(unsigned int, o[3]) };
        uint4 s1 = { __builtin_bit_cast(unsigned int, o[4]), __builtin_bit_cast(unsigned int, o[5]),
                     __builtin_bit_cast(unsigned int, o[6]), __builtin_bit_cast(unsigned int, o[7]) };
        *(uint4*)orow = s0;
        *(uint4*)(orow + 16) = s1;
    }
}

// ============================ Two-stage pooling ============================
__global__ __launch_bounds__(256) void pool_partial(
    const _Float16* __restrict__ h, const int* __restrict__ startg,
    const int* __restrict__ endg, float* __restrict__ sumP, float* __restrict__ maxP)
{
    __shared__ float4 sS[4][64];
    __shared__ float4 sM[4][64];
    int g = blockIdx.x >> 5, part = blockIdx.x & (NPART - 1);
    int lane = threadIdx.x & 63;
    int sub = threadIdx.x >> 6;
    int c0 = lane * 4;
    int s = startg[g], e = endg[g];
    float4 sum = make_float4(0.f, 0.f, 0.f, 0.f);
    float4 mx = make_float4(-INFINITY, -INFINITY, -INFINITY, -INFINITY);
    for (int i = s + part * 4 + sub; i < e; i += NPART * 4) {
        uint2 u = *(const uint2*)&h[(size_t)i * HCDIM + c0];
        h2 a = bch2(u.x), b = bch2(u.y);
        float4 v = make_float4((float)a.x, (float)a.y, (float)b.x, (float)b.y);
        sum.x += v.x; sum.y += v.y; sum.z += v.z; sum.w += v.w;
        mx.x = fmaxf(mx.x, v.x); mx.y = fmaxf(mx.y, v.y);
        mx.z = fmaxf(mx.z, v.z); mx.w = fmaxf(mx.w, v.w);
    }
    sS[sub][lane] = sum; sM[sub][lane] = mx;
    __syncthreads();
    if (sub == 0) {
        #pragma unroll
        for (int j = 1; j < 4; ++j) {
            float4 a = sS[j][lane], b = sM[j][lane];
            sum.x += a.x; sum.y += a.y; sum.z += a.z; sum.w += a.w;
            mx.x = fmaxf(mx.x, b.x); mx.y = fmaxf(mx.y, b.y);
            mx.z = fmaxf(mx.z, b.z); mx.w = fmaxf(mx.w, b.w);
        }
        size_t o = (size_t)blockIdx.x * HCDIM + c0;
        *(float4*)&sumP[o] = sum;
        *(float4*)&maxP[o] = mx;
    }
}

// Stage 2 + logits + softmax fused
__global__ __launch_bounds__(256) void pool_final_logits(
    const float* __restrict__ sumP, const float* __restrict__ maxP,
    const int* __restrict__ startg, const int* __restrict__ endg,
    const float* __restrict__ Wout, const float* __restrict__ bout,
    float* __restrict__ out)
{
    __shared__ float red[256];
    __shared__ float lg[NCLS];
    int g = blockIdx.x, c = threadIdx.x;
    float s = 0.f, m = -INFINITY;
    #pragma unroll 8
    for (int part = 0; part < NPART; ++part) {
        size_t o = (size_t)(g * NPART + part) * HCDIM + c;
        s += sumP[o];
        m = fmaxf(m, maxP[o]);
    }
    int cnt = endg[g] - startg[g];
    float inv = 1.f / fmaxf((float)cnt, 1.f);
    float pv = s * inv + m;

    for (int j = 0; j < NCLS; ++j) {
        red[c] = pv * Wout[c * NCLS + j];
        __syncthreads();
        for (int off = 128; off > 0; off >>= 1) {
            if (c < off) red[c] += red[c + off];
            __syncthreads();
        }
        if (c == 0) lg[j] = red[0] + bout[j];
        __syncthreads();
    }
    if (c == 0) {
        float mx = fmaxf(lg[0], fmaxf(lg[1], lg[2]));
        float e0 = __expf(lg[0] - mx), e1 = __expf(lg[1] - mx), e2 = __expf(lg[2] - mx);
        float invs = 1.f / (e0 + e1 + e2);
        out[g * NCLS + 0] = e0 * invs;
        out[g * NCLS + 1] = e1 * invs;
        out[g * NCLS + 2] = e2 * invs;
    }
}

// ============================ Orchestration ============================
extern "C" void kernel_launch(void* const* d_in, const int* in_sizes, int n_in,
                              void* d_out, int out_size, void* d_ws, size_t ws_size,
                              hipStream_t stream) {
    const float* x     = (const float*)d_in[0];
    const int*   ei    = (const int*)d_in[1];
    const int*   batch = (const int*)d_in[2];
    const float *Wl[3], *bl[3], *Wr[3], *br[3], *att[3], *bias[3];
    for (int li = 0; li < 3; ++li) {
        int b = 3 + li * 6;
        Wl[li]   = (const float*)d_in[b + 0];
        bl[li]   = (const float*)d_in[b + 1];
        Wr[li]   = (const float*)d_in[b + 2];
        br[li]   = (const float*)d_in[b + 3];
        att[li]  = (const float*)d_in[b + 4];
        bias[li] = (const float*)d_in[b + 5];
    }
    const float* Wout = (const float*)d_in[21];
    const float* bout = (const float*)d_in[22];
    float* out = (float*)d_out;

    size_t off = 0;
    char* wsb = (char*)d_ws;
    auto alloc = [&](size_t bytes) -> char* {
        char* ptr = wsb + off;
        off += (bytes + 255) & ~(size_t)255;
        return ptr;
    };
    // zeroed region: cnt | startg | endg | dhist
    int* zblk    = (int*)alloc((N_NODES + 2 * NGRAPH + DBINS) * sizeof(int));
    int* cnt     = zblk;
    int* startg  = zblk + N_NODES;
    int* endg    = zblk + N_NODES + NGRAPH;
    int* dhist   = zblk + N_NODES + 2 * NGRAPH;
    int* colx    = (int*)alloc((size_t)COLX_SZ * sizeof(int));   // zeroed (bucket CSR)
    int* bcnt    = (int*)alloc(SCAN_NB * DBINS * sizeof(int));
    int* meta    = (int*)alloc(N_NODES * sizeof(int));
    _Float16* Abuf = (_Float16*)alloc((size_t)MPAD * HCDIM * sizeof(_Float16));
    _Float16* Bt[3];
    for (int li = 0; li < 3; ++li) {
        int K = (li == 0) ? F_INPUT : HCDIM;
        Bt[li] = (_Float16*)alloc((size_t)512 * K * sizeof(_Float16));
    }
    unsigned char* xl8 = (unsigned char*)alloc((size_t)N_NODES * HCDIM);
    _Float16* xrh  = (_Float16*)alloc((size_t)N_NODES * HCDIM * sizeof(_Float16));
    _Float16* hbuf = (_Float16*)alloc((size_t)N_NODES * HCDIM * sizeof(_Float16));
    float* sumP    = (float*)alloc((size_t)NGRAPH * NPART * HCDIM * sizeof(float));
    float* maxP    = (float*)alloc((size_t)NGRAPH * NPART * HCDIM * sizeof(float));

    hipMemsetAsync(zblk, 0, (N_NODES + 2 * NGRAPH + DBINS) * sizeof(int), stream);
    hipMemsetAsync(colx, 0, (size_t)COLX_SZ * sizeof(int), stream);

    hist_prep_kernel<<<HP_NB, 256, 0, stream>>>(
        ei, cnt, colx, batch, startg, endg,
        x, Abuf, Bt[0], Bt[1], Bt[2],
        Wl[0], Wr[0], Wl[1], Wr[1], Wl[2], Wr[2]);
    degh_kernel<<<SCAN_NB, 256, 0, stream>>>(cnt, dhist, bcnt);
    binscan_kernel<<<1, 256, 0, stream>>>(dhist, bcnt);

    // layer 0: degree-sorted meta scatter fused with the layer-0 GEMM
    fill_gemm_kernel<<<FG_NB, 256, 0, stream>>>(
        cnt, bcnt, meta,
        Abuf, Bt[0], bl[0], br[0], xl8, xrh);
    gat_edge<<<EDGE_CHUNKS * 4, 256, 0, stream>>>(
        xl8, xrh, att[0], bias[0], meta, colx, nullptr, Abuf, 1);

    for (int li = 1; li < 3; ++li) {
        gemm_mfma<<<GEMM_NB, 256, 0, stream>>>(
            Abuf, Bt[li], HCDIM, bl[li], br[li], xl8, xrh);
        if (li < 2) {
            gat_edge<<<EDGE_CHUNKS * 4, 256, 0, stream>>>(
                xl8, xrh, att[li], bias[li], meta, colx, nullptr, Abuf, 1);
        } else {
            gat_edge<<<EDGE_CHUNKS * 4, 256, 0, stream>>>(
                xl8, xrh, att[li], bias[li], meta, colx, hbuf, nullptr, 0);
        }
    }

    pool_partial<<<NGRAPH * NPART, 256, 0, stream>>>(hbuf, startg, endg, sumP, maxP);
    pool_final_logits<<<NGRAPH, 256, 0, stream>>>(sumP, maxP, startg, endg, Wout, bout, out);
}

// Round 19
// 363.605 us; speedup vs baseline: 1.0570x; 1.0570x over previous
//
#include <hip/hip_runtime.h>
#include <math.h>

#define N_NODES 50000
#define N_EDGES 600000
#define F_INPUT 128
#define HCDIM 256
#define NGRAPH 64
#define NCLS 3
#define MPAD 50048   // 782 * 64, GEMM M padded
#define SCAN_NB ((N_NODES + 255) / 256)   // 196
#define LOG2E 1.4426950408889634f
#define NPART 32     // pooling partitions per graph
#define TOTAL_E (N_EDGES + N_NODES)
#define PLANE64 ((size_t)N_NODES * 64)    // bytes (fp8) / elements per head plane
#define EDGE_CHUNKS ((N_NODES + 63) / 64) // 782
#define DBINS 64     // degree-sort bins (deg clamped to 63 for binning only)
#define BSEG (SCAN_NB / 4)   // 49 blocks per scan segment (196 = 4*49)
#define GEMM_NB ((MPAD / 64) * 4)   // 3128 blocks = 8 XCDs * 391
#define GEMM_QPX (GEMM_NB / 8)      // 391 blocks per XCD (exact)
#define BUCKET 64                    // colx slots per node (max deg ~35 << 64)
#define COLX_SZ (N_NODES * BUCKET + 128)  // +128 zero pad for prefetch overrun
#define NPX ((N_NODES + 7) / 8)      // 6250 nodes per XCD partition

// ---- fused hist+boundary+prep: XCD-partitioned single-pass bucket CSR scatter ----
#define HIST_CH   ((TOTAL_E + 255) / 256)               // 2540 chunks
#define HIST_NB   (HIST_CH * 8)                         // 20320
#define BND_NB    ((N_NODES + 255) / 256)               // 196
#define SPLITX_NB (MPAD * F_INPUT / 4 / 256)            // 6256
#define ZERO_NB   (((MPAD - N_NODES) * HCDIM / 4 + 255) / 256)  // 12
#define WPREP_NB  (512 * (F_INPUT + HCDIM + HCDIM) / 256)       // 1280
#define HP_NB     (HIST_NB + BND_NB + SPLITX_NB + ZERO_NB + WPREP_NB)
// ---- fused meta-scatter + gemm0 ----
#define FG_NB     (SCAN_NB + GEMM_NB)                   // 3324

typedef float f32x4 __attribute__((ext_vector_type(4)));
typedef float f32x2 __attribute__((ext_vector_type(2)));
typedef _Float16 f16x8 __attribute__((ext_vector_type(8)));
typedef _Float16 f16x4 __attribute__((ext_vector_type(4)));
typedef _Float16 h2 __attribute__((ext_vector_type(2)));

__device__ __forceinline__ void gl_lds16(const void* g, void* l) {
    __builtin_amdgcn_global_load_lds(
        (const __attribute__((address_space(1))) unsigned int*)g,
        (__attribute__((address_space(3))) unsigned int*)l, 16, 0, 0);
}

__device__ __forceinline__ h2 bch2(unsigned int u) { return __builtin_bit_cast(h2, u); }
__device__ __forceinline__ h2 pk16(float a, float b) {
    return __builtin_bit_cast(h2, __builtin_amdgcn_cvt_pkrtz(a, b));
}

// 4-lane (quad) butterfly sum via DPP quad_perm — pure VALU, no LDS pipe / lgkm wait.
__device__ __forceinline__ float quad_reduce_add(float p) {
    int s1 = __builtin_amdgcn_update_dpp(0, __builtin_bit_cast(int, p), 0xB1, 0xF, 0xF, true);
    p += __builtin_bit_cast(float, s1);
    int s2 = __builtin_amdgcn_update_dpp(0, __builtin_bit_cast(int, p), 0x4E, 0xF, 0xF, true);
    p += __builtin_bit_cast(float, s2);
    return p;
}

// Shared 64x128-tile GEMM body, BK=64, single-buffered (TERMINAL configuration).
// FOUR alternatives all measured worse at this skinny shape (M=50k, N=512, K<=256):
//   BN=256 (R9: 67us), 128x128 tile (R12: 83us), BK=128 (R16: 49.6us),
//   2-phase dbuf (R18: 46.3us — 48KB LDS costs residency, overlap never pays).
// At ~2.3 resident blocks/CU the naive schedule's implicit inter-wave overlap is
// already optimal (guide m99/m100 precedent). ~42us/dispatch, MfmaUtil ~11%.
__device__ __forceinline__ void gemm_body_64(
    const _Float16* __restrict__ A, const _Float16* __restrict__ B, int K,
    const float* __restrict__ bl, const float* __restrict__ br,
    unsigned char* __restrict__ xl8, _Float16* __restrict__ xrh,
    _Float16* sA, _Float16* sB, int bx, int by)
{
    int tid = threadIdx.x;
    int lane = tid & 63, wave = tid >> 6;
    int wm = wave >> 1, wn = wave & 1;
    int row0 = bx * 64;
    int n0 = by * 128;
    int quad = lane >> 4, l16 = lane & 15;

    f32x4 acc[2][4];
    #pragma unroll
    for (int i = 0; i < 2; ++i)
        #pragma unroll
        for (int j = 0; j < 4; ++j)
            acc[i][j] = (f32x4){0.f, 0.f, 0.f, 0.f};

    for (int k0 = 0; k0 < K; k0 += 64) {
        __syncthreads();
        #pragma unroll
        for (int pass = 0; pass < 2; ++pass) {
            int c = tid + pass * 256;           // A chunk 0..511
            int r = c >> 3;
            int pl = c & 7;
            int pg = pl ^ (r & 7);
            size_t ga = (size_t)(row0 + r) * K + k0 + pg * 8;
            gl_lds16(A + ga, sA + c * 8);
        }
        #pragma unroll
        for (int pass = 0; pass < 4; ++pass) {
            int c = tid + pass * 256;           // B chunk 0..1023
            int r = c >> 3;
            int pl = c & 7;
            int pg = pl ^ (r & 7);
            size_t gb = (size_t)(n0 + r) * K + k0 + pg * 8;
            gl_lds16(B + gb, sB + c * 8);
        }
        __syncthreads();

        #pragma unroll
        for (int kk = 0; kk < 2; ++kk) {
            f16x8 fa[2], fb[4];
            #pragma unroll
            for (int i = 0; i < 2; ++i) {
                int rr = wm * 32 + i * 16 + l16;
                int ca = (kk * 4 + quad) ^ (rr & 7);
                fa[i] = *(const f16x8*)&sA[rr * 64 + ca * 8];
            }
            #pragma unroll
            for (int j = 0; j < 4; ++j) {
                int nn = wn * 64 + j * 16 + l16;
                int cb = (kk * 4 + quad) ^ (nn & 7);
                fb[j] = *(const f16x8*)&sB[nn * 64 + cb * 8];
            }
            #pragma unroll
            for (int i = 0; i < 2; ++i)
                #pragma unroll
                for (int j = 0; j < 4; ++j)
                    acc[i][j] = __builtin_amdgcn_mfma_f32_16x16x32_f16(fa[i], fb[j], acc[i][j], 0, 0, 0);
        }
    }

    if (by < 2) {
        int cb0 = by * 128;
        #pragma unroll
        for (int j = 0; j < 4; ++j) {
            int col = cb0 + wn * 64 + j * 16 + l16;
            float bj = bl[col];
            int hh = col >> 6, c64 = col & 63;
            unsigned char* xlp = xl8 + (size_t)hh * PLANE64;
            #pragma unroll
            for (int i = 0; i < 2; ++i) {
                int rbase = row0 + wm * 32 + i * 16 + quad * 4;
                #pragma unroll
                for (int r = 0; r < 4; ++r) {
                    int row = rbase + r;
                    if (row < N_NODES) {
                        float v = acc[i][j][r] + bj;
                        int pk = __builtin_amdgcn_cvt_pk_fp8_f32(v, v, 0, false);
                        xlp[(size_t)row * 64 + c64] = (unsigned char)pk;
                    }
                }
            }
        }
    } else {
        int cb0 = (by - 2) * 128;
        #pragma unroll
        for (int j = 0; j < 4; ++j) {
            int col = cb0 + wn * 64 + j * 16 + l16;
            float bj = br[col];
            int hh = col >> 6, c64 = col & 63;
            _Float16* xrp = xrh + (size_t)hh * PLANE64;
            #pragma unroll
            for (int i = 0; i < 2; ++i) {
                int rbase = row0 + wm * 32 + i * 16 + quad * 4;
                #pragma unroll
                for (int r = 0; r < 4; ++r) {
                    int row = rbase + r;
                    if (row < N_NODES)
                        xrp[(size_t)row * 64 + c64] = (_Float16)(acc[i][j][r] + bj);
                }
            }
        }
    }
}

// ============================ Fused bucket-CSR scatter + boundary + prep ============================
__global__ void hist_prep_kernel(
    const int* __restrict__ ei, int* __restrict__ cnt, int* __restrict__ colx,
    const int* __restrict__ batch, int* __restrict__ startg, int* __restrict__ endg,
    const float* __restrict__ x, _Float16* __restrict__ A,
    _Float16* __restrict__ Bt0, _Float16* __restrict__ Bt1, _Float16* __restrict__ Bt2,
    const float* __restrict__ Wl0, const float* __restrict__ Wr0,
    const float* __restrict__ Wl1, const float* __restrict__ Wr1,
    const float* __restrict__ Wl2, const float* __restrict__ Wr2)
{
    int b = blockIdx.x;
    if (b < HIST_NB) {
        // XCD-local scatter: this block handles only dests in its XCD's node range.
        int xcd = b & 7;                       // bid%8 = XCD (round-robin dispatch)
        int i = (b >> 3) * 256 + threadIdx.x;  // edge chunk
        if (i >= TOTAL_E) return;
        int s, d;
        if (i < N_EDGES) { s = ei[i]; d = ei[N_EDGES + i]; }
        else             { s = i - N_EDGES; d = s; }
        if ((unsigned)(d - xcd * NPX) < (unsigned)NPX) {
            int slot = atomicAdd(&cnt[d], 1);
            colx[d * BUCKET + slot] = s * 64;
        }
        return;
    }
    b -= HIST_NB;
    if (b < BND_NB) {
        int i = b * 256 + threadIdx.x;
        if (i >= N_NODES) return;
        int g = batch[i];
        if (i == 0 || batch[i - 1] != g) startg[g] = i;
        if (i == N_NODES - 1 || batch[i + 1] != g) endg[g] = i + 1;
        return;
    }
    b -= BND_NB;
    if (b < SPLITX_NB) {
        int base = (b * 256 + threadIdx.x) * 4;
        int row = base >> 7;
        float4 v = make_float4(0.f, 0.f, 0.f, 0.f);
        if (row < N_NODES) v = *(const float4*)&x[base];
        f16x4 o;
        o.x = (_Float16)v.x; o.y = (_Float16)v.y; o.z = (_Float16)v.z; o.w = (_Float16)v.w;
        *(f16x4*)&A[base] = o;
    } else if (b < SPLITX_NB + ZERO_NB) {
        int i = ((b - SPLITX_NB) * 256 + threadIdx.x) * 4;
        if (i < (MPAD - N_NODES) * HCDIM) {
            f16x4 z = {(_Float16)0.f, (_Float16)0.f, (_Float16)0.f, (_Float16)0.f};
            *(f16x4*)&A[(size_t)N_NODES * HCDIM + i] = z;
        }
    } else {
        int t = (b - SPLITX_NB - ZERO_NB) * 256 + threadIdx.x;
        const float* Wl; const float* Wr; _Float16* Bt; int K;
        if (t < 512 * F_INPUT)            { Wl = Wl0; Wr = Wr0; Bt = Bt0; K = F_INPUT; }
        else if (t < 512 * (F_INPUT + HCDIM)) { t -= 512 * F_INPUT; Wl = Wl1; Wr = Wr1; Bt = Bt1; K = HCDIM; }
        else                              { t -= 512 * (F_INPUT + HCDIM); Wl = Wl2; Wr = Wr2; Bt = Bt2; K = HCDIM; }
        int n = t & 511, k = t >> 9;
        float w = (n < 256) ? Wl[k * 256 + n] : Wr[k * 256 + (n - 256)];
        Bt[n * K + k] = (_Float16)w;
    }
}

// Per-block degree histogram for the counting sort.
__global__ void degh_kernel(const int* __restrict__ cnt, int* __restrict__ dhist,
                            int* __restrict__ bcnt) {
    __shared__ int lh[DBINS];
    int b = blockIdx.x, t = threadIdx.x;
    if (t < DBINS) lh[t] = 0;
    __syncthreads();
    int i = b * 256 + t;
    if (i < N_NODES) {
        int dg = cnt[i];
        atomicAdd(&lh[dg < (DBINS - 1) ? dg : (DBINS - 1)], 1);
    }
    __syncthreads();
    if (t < DBINS) {
        bcnt[b * DBINS + t] = lh[t];
        if (lh[t] != 0) atomicAdd(&dhist[t], lh[t]);
    }
}

// Parallel counting-sort level 1 (one block)
__global__ __launch_bounds__(256) void binscan_kernel(const int* __restrict__ dhist,
                                                      int* __restrict__ bcnt) {
    __shared__ int sb[SCAN_NB * DBINS];   // 49.0 KB
    __shared__ int part[4][DBINS];
    __shared__ int binstart[DBINS];
    int t = threadIdx.x;
    for (int i = t; i < SCAN_NB * DBINS; i += 256) sb[i] = bcnt[i];
    if (t < 64) {
        int x = dhist[t];
        #pragma unroll
        for (int off = 1; off < 64; off <<= 1) {
            int y = __shfl_up(x, off, 64);
            if (t >= off) x += y;
        }
        int total = __shfl(x, 63, 64);
        binstart[t] = total - x;   // nodes with bin > t (descending order start)
    }
    __syncthreads();
    int l = t & 63, seg = t >> 6;
    int ps = 0;
    for (int b = seg * BSEG; b < (seg + 1) * BSEG; ++b) ps += sb[b * DBINS + l];
    part[seg][l] = ps;
    __syncthreads();
    int off = binstart[l];
    for (int s = 0; s < seg; ++s) off += part[s][l];
    for (int b = seg * BSEG; b < (seg + 1) * BSEG; ++b) {
        int tv = sb[b * DBINS + l];
        sb[b * DBINS + l] = off;
        off += tv;
    }
    __syncthreads();
    for (int i = t; i < SCAN_NB * DBINS; i += 256) bcnt[i] = sb[i];
}

// ============================ Fused meta-scatter + layer-0 GEMM ============================
__global__ __launch_bounds__(256) void fill_gemm_kernel(
    const int* __restrict__ cnt, const int* __restrict__ bcnt, int* __restrict__ meta,
    const _Float16* __restrict__ A, const _Float16* __restrict__ B,
    const float* __restrict__ bl, const float* __restrict__ br,
    unsigned char* __restrict__ xl8, _Float16* __restrict__ xrh)
{
    __shared__ _Float16 sA[64 * 64], sB[128 * 64];
    int bid = blockIdx.x;
    if (bid < SCAN_NB) {
        int* lcnt = (int*)sA;
        int t = threadIdx.x;
        if (t < DBINS) lcnt[t] = 0;
        __syncthreads();
        int i = bid * 256 + t;
        if (i < N_NODES) {
            int dg = cnt[i];
            int bin = dg < (DBINS - 1) ? dg : (DBINS - 1);
            int myr = atomicAdd(&lcnt[bin], 1);   // LDS atomic, intra-block only
            int pos = bcnt[bid * DBINS + bin] + myr;
            meta[pos] = (dg << 16) | i;
        }
        return;
    }
    int gbid = bid - SCAN_NB;
    int lin = (gbid & 7) * GEMM_QPX + (gbid >> 3);   // bijective: 3128 = 8*391
    gemm_body_64(A, B, F_INPUT, bl, br, xl8, xrh, sA, sB, lin >> 2, lin & 3);
}

// ============================ 64x128 MFMA GEMM (layers 1-2) ============================
__global__ __launch_bounds__(256) void gemm_mfma(
    const _Float16* __restrict__ A, const _Float16* __restrict__ B,
    int K,
    const float* __restrict__ bl, const float* __restrict__ br,
    unsigned char* __restrict__ xl8, _Float16* __restrict__ xrh)
{
    __shared__ _Float16 sA[64 * 64], sB[128 * 64];
    int bid = blockIdx.x;
    int lin = (bid & 7) * GEMM_QPX + (bid >> 3);   // bijective: 3128 = 8*391
    gemm_body_64(A, B, K, bl, br, xl8, xrh, sA, sB, lin >> 2, lin & 3);
}

// ============================ Edge phase: head planes + degree-sorted slots ============================
// Bucket CSR: node's edges at colx[node*64 .. node*64+cnt); slots beyond cnt are 0
// and overrun prefetch reads the next node's bucket / zero pad — always a valid
// plane offset, masked by (i < cnt). 4-deep gather pipeline, 2-edge unrolled, DPP.
__global__ __launch_bounds__(256) void gat_edge(
    const unsigned char* __restrict__ xl8, const _Float16* __restrict__ xrh,
    const float* __restrict__ att, const float* __restrict__ bias,
    const int* __restrict__ meta, const int* __restrict__ colx,
    _Float16* __restrict__ outh, _Float16* __restrict__ onext, int mode)
{
    int head = blockIdx.x & 3;
    int chunk = blockIdx.x >> 2;
    int wave = threadIdx.x >> 6;
    int lane = threadIdx.x & 63;
    int g  = lane >> 2;          // slot within wave (0..15)
    int ll = lane & 3;           // 16-ch slot within head
    int slot = chunk * 64 + wave * 16 + g;
    bool valid = slot < N_NODES;
    int saddr = valid ? slot : 0;
    int mi = meta[saddr];
    int node = mi & 0xFFFF;
    int cnt = valid ? (mi >> 16) : 0;
    int ch0 = head * 64 + ll * 16;

    int niter = cnt;
    niter = max(niter, __shfl_xor(niter, 4, 64));
    niter = max(niter, __shfl_xor(niter, 8, 64));
    niter = max(niter, __shfl_xor(niter, 16, 64));
    niter = max(niter, __shfl_xor(niter, 32, 64));

    const char* xrrow = (const char*)(xrh + (size_t)head * PLANE64)
                        + ((size_t)node * 64 + ll * 16) * 2;
    uint4 xu0 = *(const uint4*)xrrow;
    uint4 xu1 = *(const uint4*)(xrrow + 16);
    h2 xr[8] = { bch2(xu0.x), bch2(xu0.y), bch2(xu0.z), bch2(xu0.w),
                 bch2(xu1.x), bch2(xu1.y), bch2(xu1.z), bch2(xu1.w) };
    h2 at[8];
    #pragma unroll
    for (int i = 0; i < 8; ++i) {
        float2 av = *(const float2*)&att[ch0 + i * 2];
        at[i] = (h2){(_Float16)(av.x * LOG2E), (_Float16)(av.y * LOG2E)};
    }

    float denom = 0.f;
    f32x2 accp[8];
    #pragma unroll
    for (int i = 0; i < 8; ++i) accp[i] = (f32x2){0.f, 0.f};

    const unsigned char* xb = xl8 + (size_t)head * PLANE64 + ll * 16;
    const int* cxp = colx + (node << 6);   // this node's bucket
    const h2 slope = {(_Float16)0.2f, (_Float16)0.2f};

    auto process = [&](uint4 dd, int i) {
        unsigned int dw[4] = {dd.x, dd.y, dd.z, dd.w};
        f32x2 lo[4], hi[4];
        h2 hx[8];
        #pragma unroll
        for (int j = 0; j < 4; ++j) {
            lo[j] = __builtin_amdgcn_cvt_pk_f32_fp8(dw[j], false);
            hi[j] = __builtin_amdgcn_cvt_pk_f32_fp8(dw[j], true);
            hx[2 * j]     = pk16(lo[j].x, lo[j].y);
            hx[2 * j + 1] = pk16(hi[j].x, hi[j].y);
        }
        float pa = 0.f, pb = 0.f;
        #pragma unroll
        for (int j = 0; j < 4; ++j) {
            h2 va = hx[j] + xr[j];
            h2 vb = hx[j + 4] + xr[j + 4];
            va = __builtin_elementwise_max(va, va * slope);   // lrelu(0.2) = max(v, 0.2v)
            vb = __builtin_elementwise_max(vb, vb * slope);
            pa = __builtin_amdgcn_fdot2(va, at[j], pa, false);
            pb = __builtin_amdgcn_fdot2(vb, at[j + 4], pb, false);
        }
        float p = quad_reduce_add(pa + pb);
        float w = (i < cnt) ? exp2f(p) : 0.f;
        denom += w;
        f32x2 wp = {w, w};
        #pragma unroll
        for (int j = 0; j < 4; ++j) {
            accp[2 * j]     += wp * lo[j];   // -> v_pk_fma_f32
            accp[2 * j + 1] += wp * hi[j];
        }
    };

    // pipeline prologue: 4 gathers in flight (edges 0..3), colx staged for 4,5.
    uint4 d0 = *(const uint4*)(xb + (unsigned)cxp[0]);
    uint4 d1 = *(const uint4*)(xb + (unsigned)cxp[1]);
    uint4 d2 = *(const uint4*)(xb + (unsigned)cxp[2]);
    uint4 d3 = *(const uint4*)(xb + (unsigned)cxp[3]);
    int cx_a = cxp[4];
    int cx_b = cxp[5];

    int i = 0;
    for (; i + 2 <= niter; i += 2) {
        uint4 n0 = *(const uint4*)(xb + (unsigned)cx_a);   // gathers edges i+4, i+5
        uint4 n1 = *(const uint4*)(xb + (unsigned)cx_b);
        cx_a = cxp[i + 6];       // overrun lands in next bucket / zero pad — safe
        cx_b = cxp[i + 7];
        process(d0, i);          // two independent chains -> ILP
        process(d1, i + 1);
        d0 = d2; d1 = d3;        // rotate the 4-deep gather queue
        d2 = n0; d3 = n1;
    }
    if (i < niter) process(d0, i);   // odd tail (gather already in flight)

    if (valid) {
        float inv = 1.f / denom;
        char* orow = (char*)(mode == 0 ? outh : onext)
                     + (size_t)node * (HCDIM * 2) + ch0 * 2;
        h2 o[8];
        #pragma unroll
        for (int i2 = 0; i2 < 8; ++i2) {
            float2 bv = *(const float2*)&bias[ch0 + i2 * 2];
            float v0 = accp[i2].x * inv + bv.x;
            float v1 = accp[i2].y * inv + bv.y;
            if (mode != 0) { v0 = fmaxf(v0, 0.f); v1 = fmaxf(v1, 0.f); }
            o[i2] = pk16(v0, v1);
        }
        uint4 s0 = { __builtin_bit_cast(unsigned int, o[0]), __builtin_bit_cast(unsigned int, o[1]),
                     __builtin_bit_cast(unsigned int, o[2]), __builtin_bit_cast(unsigned int, o[3]) };
        uint4 s1 = { __builtin_bit_cast(unsigned int, o[4]), __builtin_bit_cast(unsigned int, o[5]),
                     __builtin_bit_cast(unsigned int, o[6]), __builtin_bit_cast(unsigned int, o[7]) };
        *(uint4*)orow = s0;
        *(uint4*)(orow + 16) = s1;
    }
}

// ============================ Two-stage pooling ============================
__global__ __launch_bounds__(256) void pool_partial(
    const _Float16* __restrict__ h, const int* __restrict__ startg,
    const int* __restrict__ endg, float* __restrict__ sumP, float* __restrict__ maxP)
{
    __shared__ float4 sS[4][64];
    __shared__ float4 sM[4][64];
    int g = blockIdx.x >> 5, part = blockIdx.x & (NPART - 1);
    int lane = threadIdx.x & 63;
    int sub = threadIdx.x >> 6;
    int c0 = lane * 4;
    int s = startg[g], e = endg[g];
    float4 sum = make_float4(0.f, 0.f, 0.f, 0.f);
    float4 mx = make_float4(-INFINITY, -INFINITY, -INFINITY, -INFINITY);
    for (int i = s + part * 4 + sub; i < e; i += NPART * 4) {
        uint2 u = *(const uint2*)&h[(size_t)i * HCDIM + c0];
        h2 a = bch2(u.x), b = bch2(u.y);
        float4 v = make_float4((float)a.x, (float)a.y, (float)b.x, (float)b.y);
        sum.x += v.x; sum.y += v.y; sum.z += v.z; sum.w += v.w;
        mx.x = fmaxf(mx.x, v.x); mx.y = fmaxf(mx.y, v.y);
        mx.z = fmaxf(mx.z, v.z); mx.w = fmaxf(mx.w, v.w);
    }
    sS[sub][lane] = sum; sM[sub][lane] = mx;
    __syncthreads();
    if (sub == 0) {
        #pragma unroll
        for (int j = 1; j < 4; ++j) {
            float4 a = sS[j][lane], b = sM[j][lane];
            sum.x += a.x; sum.y += a.y; sum.z += a.z; sum.w += a.w;
            mx.x = fmaxf(mx.x, b.x); mx.y = fmaxf(mx.y, b.y);
            mx.z = fmaxf(mx.z, b.z); mx.w = fmaxf(mx.w, b.w);
        }
        size_t o = (size_t)blockIdx.x * HCDIM + c0;
        *(float4*)&sumP[o] = sum;
        *(float4*)&maxP[o] = mx;
    }
}

// Stage 2 + logits + softmax fused
__global__ __launch_bounds__(256) void pool_final_logits(
    const float* __restrict__ sumP, const float* __restrict__ maxP,
    const int* __restrict__ startg, const int* __restrict__ endg,
    const float* __restrict__ Wout, const float* __restrict__ bout,
    float* __restrict__ out)
{
    __shared__ float red[256];
    __shared__ float lg[NCLS];
    int g = blockIdx.x, c = threadIdx.x;
    float s = 0.f, m = -INFINITY;
    #pragma unroll 8
    for (int part = 0; part < NPART; ++part) {
        size_t o = (size_t)(g * NPART + part) * HCDIM + c;
        s += sumP[o];
        m = fmaxf(m, maxP[o]);
    }
    int cnt = endg[g] - startg[g];
    float inv = 1.f / fmaxf((float)cnt, 1.f);
    float pv = s * inv + m;

    for (int j = 0; j < NCLS; ++j) {
        red[c] = pv * Wout[c * NCLS + j];
        __syncthreads();
        for (int off = 128; off > 0; off >>= 1) {
            if (c < off) red[c] += red[c + off];
            __syncthreads();
        }
        if (c == 0) lg[j] = red[0] + bout[j];
        __syncthreads();
    }
    if (c == 0) {
        float mx = fmaxf(lg[0], fmaxf(lg[1], lg[2]));
        float e0 = __expf(lg[0] - mx), e1 = __expf(lg[1] - mx), e2 = __expf(lg[2] - mx);
        float invs = 1.f / (e0 + e1 + e2);
        out[g * NCLS + 0] = e0 * invs;
        out[g * NCLS + 1] = e1 * invs;
        out[g * NCLS + 2] = e2 * invs;
    }
}

// ============================ Orchestration ============================
extern "C" void kernel_launch(void* const* d_in, const int* in_sizes, int n_in,
                              void* d_out, int out_size, void* d_ws, size_t ws_size,
                              hipStream_t stream) {
    const float* x     = (const float*)d_in[0];
    const int*   ei    = (const int*)d_in[1];
    const int*   batch = (const int*)d_in[2];
    const float *Wl[3], *bl[3], *Wr[3], *br[3], *att[3], *bias[3];
    for (int li = 0; li < 3; ++li) {
        int b = 3 + li * 6;
        Wl[li]   = (const float*)d_in[b + 0];
        bl[li]   = (const float*)d_in[b + 1];
        Wr[li]   = (const float*)d_in[b + 2];
        br[li]   = (const float*)d_in[b + 3];
        att[li]  = (const float*)d_in[b + 4];
        bias[li] = (const float*)d_in[b + 5];
    }
    const float* Wout = (const float*)d_in[21];
    const float* bout = (const float*)d_in[22];
    float* out = (float*)d_out;

    size_t off = 0;
    char* wsb = (char*)d_ws;
    auto alloc = [&](size_t bytes) -> char* {
        char* ptr = wsb + off;
        off += (bytes + 255) & ~(size_t)255;
        return ptr;
    };
    // zeroed region: cnt | startg | endg | dhist
    int* zblk    = (int*)alloc((N_NODES + 2 * NGRAPH + DBINS) * sizeof(int));
    int* cnt     = zblk;
    int* startg  = zblk + N_NODES;
    int* endg    = zblk + N_NODES + NGRAPH;
    int* dhist   = zblk + N_NODES + 2 * NGRAPH;
    int* colx    = (int*)alloc((size_t)COLX_SZ * sizeof(int));   // zeroed (bucket CSR)
    int* bcnt    = (int*)alloc(SCAN_NB * DBINS * sizeof(int));
    int* meta    = (int*)alloc(N_NODES * sizeof(int));
    _Float16* Abuf = (_Float16*)alloc((size_t)MPAD * HCDIM * sizeof(_Float16));
    _Float16* Bt[3];
    for (int li = 0; li < 3; ++li) {
        int K = (li == 0) ? F_INPUT : HCDIM;
        Bt[li] = (_Float16*)alloc((size_t)512 * K * sizeof(_Float16));
    }
    unsigned char* xl8 = (unsigned char*)alloc((size_t)N_NODES * HCDIM);
    _Float16* xrh  = (_Float16*)alloc((size_t)N_NODES * HCDIM * sizeof(_Float16));
    _Float16* hbuf = (_Float16*)alloc((size_t)N_NODES * HCDIM * sizeof(_Float16));
    float* sumP    = (float*)alloc((size_t)NGRAPH * NPART * HCDIM * sizeof(float));
    float* maxP    = (float*)alloc((size_t)NGRAPH * NPART * HCDIM * sizeof(float));

    hipMemsetAsync(zblk, 0, (N_NODES + 2 * NGRAPH + DBINS) * sizeof(int), stream);
    hipMemsetAsync(colx, 0, (size_t)COLX_SZ * sizeof(int), stream);

    hist_prep_kernel<<<HP_NB, 256, 0, stream>>>(
        ei, cnt, colx, batch, startg, endg,
        x, Abuf, Bt[0], Bt[1], Bt[2],
        Wl[0], Wr[0], Wl[1], Wr[1], Wl[2], Wr[2]);
    degh_kernel<<<SCAN_NB, 256, 0, stream>>>(cnt, dhist, bcnt);
    binscan_kernel<<<1, 256, 0, stream>>>(dhist, bcnt);

    // layer 0: degree-sorted meta scatter fused with the layer-0 GEMM
    fill_gemm_kernel<<<FG_NB, 256, 0, stream>>>(
        cnt, bcnt, meta,
        Abuf, Bt[0], bl[0], br[0], xl8, xrh);
    gat_edge<<<EDGE_CHUNKS * 4, 256, 0, stream>>>(
        xl8, xrh, att[0], bias[0], meta, colx, nullptr, Abuf, 1);

    for (int li = 1; li < 3; ++li) {
        gemm_mfma<<<GEMM_NB, 256, 0, stream>>>(
            Abuf, Bt[li], HCDIM, bl[li], br[li], xl8, xrh);
        if (li < 2) {
            gat_edge<<<EDGE_CHUNKS * 4, 256, 0, stream>>>(
                xl8, xrh, att[li], bias[li], meta, colx, nullptr, Abuf, 1);
        } else {
            gat_edge<<<EDGE_CHUNKS * 4, 256, 0, stream>>>(
                xl8, xrh, att[li], bias[li], meta, colx, hbuf, nullptr, 0);
        }
    }

    pool_partial<<<NGRAPH * NPART, 256, 0, stream>>>(hbuf, startg, endg, sumP, maxP);
    pool_final_logits<<<NGRAPH, 256, 0, stream>>>(sumP, maxP, startg, endg, Wout, bout, out);
}